// Round 6
// baseline (225.628 us; speedup 1.0000x reference)
//
#include <hip/hip_runtime.h>
#include <cmath>

#define B_ 32
#define S_ 4096
#define E_ 512
#define H_ 1024
#define V_ 50257
#define CHA 128   // vocab rows per score-pass block
#define CHB 197   // vocab rows per wsum-pass block (ceil(V/256))
#define NBB 256   // wsum blocks

// ---------------------------------------------------------------------------
// Kernel 1: v_t[b,e] = tanhf(dot(h[b,:], W[e,:]) + bias[e])
// ---------------------------------------------------------------------------
__global__ __launch_bounds__(256) void vt_kernel(const float* __restrict__ h,
                                                 const float* __restrict__ W,
                                                 const float* __restrict__ bias,
                                                 float* __restrict__ vt) {
    int wid  = threadIdx.x >> 6;
    int lane = threadIdx.x & 63;
    int out  = blockIdx.x * 4 + wid;        // 0 .. B*E-1
    int b    = out >> 9;
    int e    = out & (E_ - 1);
    const float* hrow = h + b * H_;
    const float* wrow = W + (size_t)e * H_;
    int base = lane * 16;
    float acc = 0.f;
#pragma unroll
    for (int j = 0; j < 4; ++j) {
        float4 hv = *reinterpret_cast<const float4*>(hrow + base + j * 4);
        float4 wv = *reinterpret_cast<const float4*>(wrow + base + j * 4);
        acc += hv.x * wv.x + hv.y * wv.y + hv.z * wv.z + hv.w * wv.w;
    }
#pragma unroll
    for (int off = 32; off > 0; off >>= 1) acc += __shfl_xor(acc, off, 64);
    if (lane == 0) vt[out] = tanhf(acc + bias[e]);
}

// ---------------------------------------------------------------------------
// Kernel 2: histogram counts[b][v] += 1 over mems. Low contention (1.6M ctrs).
// ---------------------------------------------------------------------------
__global__ __launch_bounds__(256) void hist_kernel(const int* __restrict__ mems,
                                                   int* __restrict__ counts) {
    int i = blockIdx.x * 256 + threadIdx.x;   // grid = 512 -> exactly B*S
    int b = i >> 12;                           // / S_
    atomicAdd(counts + (size_t)b * V_ + mems[i], 1);
}

// ---------------------------------------------------------------------------
// Kernel 3 (pass A): scores[b][v] = dot(emb[v], vt[b]).  Dense GEMM-style:
// block = 128 vocab rows x all 32 b; thread owns 4b x 4v; K tiled by 64 with
// XOR-swizzled LDS emb tile (16B slots, slot = k4 ^ ((row>>2)&15)).
// ---------------------------------------------------------------------------
#define DOT4(t, e) ((t).x*(e).x + (t).y*(e).y + (t).z*(e).z + (t).w*(e).w)

__global__ __launch_bounds__(256) void score_kernel(const float* __restrict__ emb,
                                                    const float* __restrict__ vt,
                                                    float* __restrict__ scores) {
    const int tid   = threadIdx.x;
    const int vbase = blockIdx.x * CHA;
    const int bh = tid >> 5;           // 0..7  -> b0 = bh*4
    const int vh = tid & 31;           // 0..31 -> v0 = vh*4
    const int b0 = bh * 4;
    const int v0 = vh * 4;

    __shared__ float4 s_emb[CHA][16];  // k-tile, swizzled 16B slots
    __shared__ float4 s_vt[32][16];

    float acc[16];
#pragma unroll
    for (int i = 0; i < 16; ++i) acc[i] = 0.f;

    for (int kt = 0; kt < E_; kt += 64) {
        __syncthreads();
        // stage emb tile: 128 rows x 64 k = 2048 float4, 8 per thread
#pragma unroll
        for (int j = 0; j < 8; ++j) {
            int f4  = tid + j * 256;
            int row = f4 >> 4;
            int c4  = f4 & 15;
            int grow = vbase + row; if (grow > V_ - 1) grow = V_ - 1;
            float4 val = *reinterpret_cast<const float4*>(emb + (size_t)grow * E_ + kt + c4 * 4);
            s_emb[row][c4 ^ ((row >> 2) & 15)] = val;
        }
        // stage vt tile: 32 rows x 64 k = 512 float4, 2 per thread
#pragma unroll
        for (int j = 0; j < 2; ++j) {
            int f4  = tid + j * 256;
            int row = f4 >> 4;
            int c4  = f4 & 15;
            s_vt[row][c4] = *reinterpret_cast<const float4*>(vt + row * E_ + kt + c4 * 4);
        }
        __syncthreads();
#pragma unroll
        for (int k4 = 0; k4 < 16; ++k4) {
            float4 tv0 = s_vt[b0 + 0][k4];
            float4 tv1 = s_vt[b0 + 1][k4];
            float4 tv2 = s_vt[b0 + 2][k4];
            float4 tv3 = s_vt[b0 + 3][k4];
            float4 e0 = s_emb[v0 + 0][k4 ^ (((v0 + 0) >> 2) & 15)];
            float4 e1 = s_emb[v0 + 1][k4 ^ (((v0 + 1) >> 2) & 15)];
            float4 e2 = s_emb[v0 + 2][k4 ^ (((v0 + 2) >> 2) & 15)];
            float4 e3 = s_emb[v0 + 3][k4 ^ (((v0 + 3) >> 2) & 15)];
            acc[0]  += DOT4(tv0, e0); acc[1]  += DOT4(tv0, e1);
            acc[2]  += DOT4(tv0, e2); acc[3]  += DOT4(tv0, e3);
            acc[4]  += DOT4(tv1, e0); acc[5]  += DOT4(tv1, e1);
            acc[6]  += DOT4(tv1, e2); acc[7]  += DOT4(tv1, e3);
            acc[8]  += DOT4(tv2, e0); acc[9]  += DOT4(tv2, e1);
            acc[10] += DOT4(tv2, e2); acc[11] += DOT4(tv2, e3);
            acc[12] += DOT4(tv3, e0); acc[13] += DOT4(tv3, e1);
            acc[14] += DOT4(tv3, e2); acc[15] += DOT4(tv3, e3);
        }
    }
#pragma unroll
    for (int j = 0; j < 4; ++j) {
        size_t base = (size_t)(b0 + j) * V_;
#pragma unroll
        for (int i = 0; i < 4; ++i) {
            int v = vbase + v0 + i;
            if (v < V_) scores[base + v] = acc[j * 4 + i];
        }
    }
}

// ---------------------------------------------------------------------------
// Kernel 4: per-(b,slice) online max/sum over scores where counts>0.
// grid 256: b = blk>>3, slice = blk&7.
// ---------------------------------------------------------------------------
__global__ __launch_bounds__(256) void reduce1_kernel(const int* __restrict__ counts,
                                                      const float* __restrict__ scores,
                                                      float2* __restrict__ mlpart) {
    int blk = blockIdx.x;
    int b = blk >> 3, slice = blk & 7;
    const int per = (V_ + 7) / 8;
    int beg = slice * per;
    int end = beg + per; if (end > V_) end = V_;
    float m = -1e30f, l = 0.f;
    for (int v = beg + threadIdx.x; v < end; v += 256) {
        int c = counts[(size_t)b * V_ + v];
        if (c) {
            float s = scores[(size_t)b * V_ + v];
            float mn = fmaxf(m, s);
            l = l * __expf(m - mn) + (float)c * __expf(s - mn);
            m = mn;
        }
    }
#pragma unroll
    for (int off = 32; off > 0; off >>= 1) {
        float m2 = __shfl_xor(m, off, 64);
        float l2 = __shfl_xor(l, off, 64);
        float mn = fmaxf(m, m2);
        l = l * __expf(m - mn) + l2 * __expf(m2 - mn);
        m = mn;
    }
    __shared__ float sm[4], sl[4];
    if ((threadIdx.x & 63) == 0) { sm[threadIdx.x >> 6] = m; sl[threadIdx.x >> 6] = l; }
    __syncthreads();
    if (threadIdx.x == 0) {
        float M = sm[0], L = sl[0];
        for (int wv = 1; wv < 4; ++wv) {
            float mn = fmaxf(M, sm[wv]);
            L = L * __expf(M - mn) + sl[wv] * __expf(sm[wv] - mn);
            M = mn;
        }
        mlpart[b * 8 + slice] = make_float2(M, L);
    }
}

// Kernel 5: merge 8 slices per b -> ml[b] = (m_b, 1/l_b)
__global__ __launch_bounds__(64) void reduce2_kernel(const float2* __restrict__ mlpart,
                                                     float2* __restrict__ ml) {
    int b = threadIdx.x;
    if (b < B_) {
        float m = -1e30f, l = 0.f;
        for (int s = 0; s < 8; ++s) {
            float2 p = mlpart[b * 8 + s];
            float mn = fmaxf(m, p.x);
            l = l * __expf(m - mn) + p.y * __expf(p.x - mn);
            m = mn;
        }
        ml[b] = make_float2(m, 1.f / l);
    }
}

// ---------------------------------------------------------------------------
// Kernel 6 (pass B): partial[blk][b][e] = sum over block's vocab rows of
// w[b][v] * emb[v][e], w = c*exp(score-m)/l. thread = e, acc[32] in regs,
// w staged 32 rows at a time in LDS (broadcast reads).
// ---------------------------------------------------------------------------
__global__ __launch_bounds__(512) void wsum_kernel(const float* __restrict__ emb,
                                                   const int* __restrict__ counts,
                                                   const float* __restrict__ scores,
                                                   const float2* __restrict__ ml,
                                                   float* __restrict__ partial) {
    int blk  = blockIdx.x;
    int rbeg = blk * CHB;
    int rend = rbeg + CHB; if (rend > V_) rend = V_;
    int e = threadIdx.x;

    __shared__ float s_w[32][36];
    __shared__ float2 s_ml[32];
    if (threadIdx.x < 32) s_ml[threadIdx.x] = ml[threadIdx.x];

    float acc[32];
#pragma unroll
    for (int b = 0; b < 32; ++b) acc[b] = 0.f;

    for (int vt0 = rbeg; vt0 < rend; vt0 += 32) {
        __syncthreads();
        for (int t = e; t < 1024; t += 512) {
            int b = t >> 5, vi = t & 31;
            int v = vt0 + vi;
            float w = 0.f;
            if (v < rend) {
                int c = counts[(size_t)b * V_ + v];
                if (c) w = (float)c * __expf(scores[(size_t)b * V_ + v] - s_ml[b].x) * s_ml[b].y;
            }
            s_w[b][vi] = w;
        }
        __syncthreads();
        int nv = rend - vt0; if (nv > 32) nv = 32;
        int vi = 0;
        for (; vi + 4 <= nv; vi += 4) {
            float ev0 = emb[(size_t)(vt0 + vi + 0) * E_ + e];
            float ev1 = emb[(size_t)(vt0 + vi + 1) * E_ + e];
            float ev2 = emb[(size_t)(vt0 + vi + 2) * E_ + e];
            float ev3 = emb[(size_t)(vt0 + vi + 3) * E_ + e];
#pragma unroll
            for (int b = 0; b < 32; ++b) {
                float4 w4 = *reinterpret_cast<const float4*>(&s_w[b][vi]);
                acc[b] += w4.x * ev0 + w4.y * ev1 + w4.z * ev2 + w4.w * ev3;
            }
        }
        for (; vi < nv; ++vi) {
            float ev = emb[(size_t)(vt0 + vi) * E_ + e];
#pragma unroll
            for (int b = 0; b < 32; ++b) acc[b] += s_w[b][vi] * ev;
        }
    }
#pragma unroll
    for (int b = 0; b < 32; ++b)
        partial[((size_t)blk * 32 + b) * E_ + e] = acc[b];
}

// Kernel 7: combine NBB partials. grid 256: b = blk>>3, e = (blk&7)*64+tid.
__global__ __launch_bounds__(64) void combine_kernel(const float* __restrict__ partial,
                                                     float* __restrict__ out) {
    int b = blockIdx.x >> 3;
    int e = (blockIdx.x & 7) * 64 + threadIdx.x;
    float s0 = 0.f, s1 = 0.f, s2 = 0.f, s3 = 0.f;
    for (int blk = 0; blk < NBB; blk += 4) {
        s0 += partial[((size_t)(blk + 0) * 32 + b) * E_ + e];
        s1 += partial[((size_t)(blk + 1) * 32 + b) * E_ + e];
        s2 += partial[((size_t)(blk + 2) * 32 + b) * E_ + e];
        s3 += partial[((size_t)(blk + 3) * 32 + b) * E_ + e];
    }
    out[(size_t)b * E_ + e] = (s0 + s1) + (s2 + s3);
}

extern "C" void kernel_launch(void* const* d_in, const int* in_sizes, int n_in,
                              void* d_out, int out_size, void* d_ws, size_t ws_size,
                              hipStream_t stream) {
    const float* h    = (const float*)d_in[0];   // [B,H]
    const int*   mems = (const int*)d_in[1];     // [B,S]
    const float* emb  = (const float*)d_in[2];   // [V,E]
    const float* W    = (const float*)d_in[3];   // [E,H]
    const float* bias = (const float*)d_in[4];   // [E]
    float* out = (float*)d_out;                  // [B,1,E]

    float* ws = (float*)d_ws;
    const size_t CNT = (size_t)B_ * V_;          // 1,608,224
    float*  vt      = ws;                                    // 16384 f
    int*    counts  = (int*)(ws + 16384);                    // CNT ints
    float*  scores  = ws + 16384 + CNT;                      // CNT f
    float2* mlpart  = (float2*)(ws + 16384 + 2 * CNT);       // 256 float2
    float2* ml      = mlpart + 256;                          // 32 float2
    float*  partial = ws + 16384 + 2 * CNT + 512 + 64;       // NBB*32*512 f

    hipMemsetAsync(counts, 0, CNT * sizeof(int), stream);

    hipLaunchKernelGGL(vt_kernel, dim3(B_ * E_ / 4), dim3(256), 0, stream,
                       h, W, bias, vt);
    hipLaunchKernelGGL(hist_kernel, dim3(B_ * S_ / 256), dim3(256), 0, stream,
                       mems, counts);
    hipLaunchKernelGGL(score_kernel, dim3((V_ + CHA - 1) / CHA), dim3(256), 0, stream,
                       emb, vt, scores);
    hipLaunchKernelGGL(reduce1_kernel, dim3(256), dim3(256), 0, stream,
                       counts, scores, mlpart);
    hipLaunchKernelGGL(reduce2_kernel, dim3(1), dim3(64), 0, stream,
                       mlpart, ml);
    hipLaunchKernelGGL(wsum_kernel, dim3(NBB), dim3(512), 0, stream,
                       emb, counts, scores, ml, partial);
    hipLaunchKernelGGL(combine_kernel, dim3(256), dim3(64), 0, stream,
                       partial, out);
}

// Round 7
// 208.170 us; speedup vs baseline: 1.0839x; 1.0839x over previous
//
#include <hip/hip_runtime.h>
#include <cmath>

#define B_ 32
#define S_ 4096
#define E_ 512
#define H_ 1024
#define V_ 50257
#define WPITCH 50304          // padded w row pitch (64-aligned)
#define CHA 64                // vocab rows per scorew block
#define NBLKA 786             // ceil(V_/CHA)
#define CHB 192               // vocab rows per wsum chunk
#define NCH 262               // ceil(V_/CHB)
#define NG 17                 // ceil(NCH/16) combine stage-1 groups

// ---------------------------------------------------------------------------
// Kernel 1: v_t[b,e] = tanhf(dot(h[b,:], W[e,:]) + bias[e])  (proven)
// ---------------------------------------------------------------------------
__global__ __launch_bounds__(256) void vt_kernel(const float* __restrict__ h,
                                                 const float* __restrict__ W,
                                                 const float* __restrict__ bias,
                                                 float* __restrict__ vt) {
    int wid  = threadIdx.x >> 6;
    int lane = threadIdx.x & 63;
    int out  = blockIdx.x * 4 + wid;
    int b    = out >> 9;
    int e    = out & (E_ - 1);
    const float* hrow = h + b * H_;
    const float* wrow = W + (size_t)e * H_;
    int base = lane * 16;
    float acc = 0.f;
#pragma unroll
    for (int j = 0; j < 4; ++j) {
        float4 hv = *reinterpret_cast<const float4*>(hrow + base + j * 4);
        float4 wv = *reinterpret_cast<const float4*>(wrow + base + j * 4);
        acc += hv.x * wv.x + hv.y * wv.y + hv.z * wv.z + hv.w * wv.w;
    }
#pragma unroll
    for (int off = 32; off > 0; off >>= 1) acc += __shfl_xor(acc, off, 64);
    if (lane == 0) vt[out] = tanhf(acc + bias[e]);
}

// ---------------------------------------------------------------------------
// Kernel 2: histogram counts[b][v] += 1 (int atomics, deterministic)
// ---------------------------------------------------------------------------
__global__ __launch_bounds__(256) void hist_kernel(const int* __restrict__ mems,
                                                   int* __restrict__ counts) {
    int i = blockIdx.x * 256 + threadIdx.x;   // grid covers exactly B*S
    int b = i >> 12;
    atomicAdd(counts + (size_t)b * V_ + mems[i], 1);
}

// ---------------------------------------------------------------------------
// Kernel 3 (pass A): w[b][v] = counts[b][v] * exp(dot(emb[v], vt[b]))
// + per-block l-partials. No max-subtraction (|score| <~ 2 by construction).
// 256 thr, tile 64v x 32b, thread = 2v x 4b. Reg-prefetch k-tile staging,
// XOR-swizzled LDS (2-way only). 786 blocks -> ~3 blocks/CU, 12 waves/CU.
// ---------------------------------------------------------------------------
#define DOT4(t, e) ((t).x*(e).x + (t).y*(e).y + (t).z*(e).z + (t).w*(e).w)

__global__ __launch_bounds__(256) void scorew_kernel(const float* __restrict__ emb,
                                                     const float* __restrict__ vt,
                                                     const int* __restrict__ counts,
                                                     float* __restrict__ w,
                                                     float* __restrict__ lpart) {
    const int tid   = threadIdx.x;
    const int vbase = blockIdx.x * CHA;
    const int vh = tid & 31;           // 0..31
    const int bh = tid >> 5;           // 0..7
    const int v0 = vh * 2;
    const int b0 = bh * 4;

    __shared__ float4 s_emb[CHA][16];  // slot = c4 ^ ((row>>1)&15)
    __shared__ float4 s_vt[32][16];
    __shared__ float  s_lp[32];

    float acc00 = 0.f, acc01 = 0.f, acc10 = 0.f, acc11 = 0.f;
    float acc20 = 0.f, acc21 = 0.f, acc30 = 0.f, acc31 = 0.f;

    // staging register buffers
    float4 se0, se1, se2, se3, sv0, sv1;
    const int er0 = tid >> 4,          ec0 = tid & 15;          // rows 0..15
    const int er1 = (tid + 256) >> 4,  ec1 = tid & 15;          // rows 16..31
    const int er2 = (tid + 512) >> 4,  ec2 = tid & 15;          // rows 32..47
    const int er3 = (tid + 768) >> 4,  ec3 = tid & 15;          // rows 48..63
    const int vr0 = tid >> 4;                                    // vt rows 0..15
    const int vr1 = (tid + 256) >> 4;                            // vt rows 16..31

    int g0 = vbase + er0; if (g0 >= V_) g0 = V_ - 1;
    int g1 = vbase + er1; if (g1 >= V_) g1 = V_ - 1;
    int g2 = vbase + er2; if (g2 >= V_) g2 = V_ - 1;
    int g3 = vbase + er3; if (g3 >= V_) g3 = V_ - 1;

    // prologue: stage k-tile 0
    se0 = *reinterpret_cast<const float4*>(emb + (size_t)g0 * E_ + ec0 * 4);
    se1 = *reinterpret_cast<const float4*>(emb + (size_t)g1 * E_ + ec1 * 4);
    se2 = *reinterpret_cast<const float4*>(emb + (size_t)g2 * E_ + ec2 * 4);
    se3 = *reinterpret_cast<const float4*>(emb + (size_t)g3 * E_ + ec3 * 4);
    sv0 = *reinterpret_cast<const float4*>(vt + vr0 * E_ + ec0 * 4);
    sv1 = *reinterpret_cast<const float4*>(vt + vr1 * E_ + ec1 * 4);
    s_emb[er0][ec0 ^ ((er0 >> 1) & 15)] = se0;
    s_emb[er1][ec1 ^ ((er1 >> 1) & 15)] = se1;
    s_emb[er2][ec2 ^ ((er2 >> 1) & 15)] = se2;
    s_emb[er3][ec3 ^ ((er3 >> 1) & 15)] = se3;
    s_vt[vr0][ec0] = sv0;
    s_vt[vr1][ec1] = sv1;
    __syncthreads();

    const int exr = (v0 >> 1) & 15;    // e-read xor (same for v0 and v0+1)

    for (int kt = 0; kt < E_; kt += 64) {
        bool more = (kt + 64) < E_;
        if (more) {
            int ko = kt + 64;
            se0 = *reinterpret_cast<const float4*>(emb + (size_t)g0 * E_ + ko + ec0 * 4);
            se1 = *reinterpret_cast<const float4*>(emb + (size_t)g1 * E_ + ko + ec1 * 4);
            se2 = *reinterpret_cast<const float4*>(emb + (size_t)g2 * E_ + ko + ec2 * 4);
            se3 = *reinterpret_cast<const float4*>(emb + (size_t)g3 * E_ + ko + ec3 * 4);
            sv0 = *reinterpret_cast<const float4*>(vt + vr0 * E_ + ko + ec0 * 4);
            sv1 = *reinterpret_cast<const float4*>(vt + vr1 * E_ + ko + ec1 * 4);
        }
#pragma unroll
        for (int k4 = 0; k4 < 16; ++k4) {
            float4 e0 = s_emb[v0][k4 ^ exr];
            float4 e1 = s_emb[v0 + 1][k4 ^ exr];
            float4 t0 = s_vt[b0 + 0][k4];
            float4 t1 = s_vt[b0 + 1][k4];
            float4 t2 = s_vt[b0 + 2][k4];
            float4 t3 = s_vt[b0 + 3][k4];
            acc00 += DOT4(t0, e0); acc01 += DOT4(t0, e1);
            acc10 += DOT4(t1, e0); acc11 += DOT4(t1, e1);
            acc20 += DOT4(t2, e0); acc21 += DOT4(t2, e1);
            acc30 += DOT4(t3, e0); acc31 += DOT4(t3, e1);
        }
        if (more) {
            __syncthreads();
            s_emb[er0][ec0 ^ ((er0 >> 1) & 15)] = se0;
            s_emb[er1][ec1 ^ ((er1 >> 1) & 15)] = se1;
            s_emb[er2][ec2 ^ ((er2 >> 1) & 15)] = se2;
            s_emb[er3][ec3 ^ ((er3 >> 1) & 15)] = se3;
            s_vt[vr0][ec0] = sv0;
            s_vt[vr1][ec1] = sv1;
            __syncthreads();
        }
    }

    // epilogue: w = c*exp(score), block l-partials
    int v = vbase + v0;
    float lp0, lp1, lp2, lp3;
    {
        float a0[4] = {acc00, acc10, acc20, acc30};
        float a1[4] = {acc01, acc11, acc21, acc31};
        float lps[4];
#pragma unroll
        for (int j = 0; j < 4; ++j) {
            int b = b0 + j;
            float w0 = 0.f, w1 = 0.f;
            if (v < V_) {
                int c = counts[(size_t)b * V_ + v];
                if (c) w0 = (float)c * __expf(a0[j]);
            }
            if (v + 1 < V_) {
                int c = counts[(size_t)b * V_ + v + 1];
                if (c) w1 = (float)c * __expf(a1[j]);
            }
            float* wp = w + (size_t)b * WPITCH + v;
            if (v + 1 < V_)      *reinterpret_cast<float2*>(wp) = make_float2(w0, w1);
            else if (v < V_)     *wp = w0;
            lps[j] = w0 + w1;
        }
        lp0 = lps[0]; lp1 = lps[1]; lp2 = lps[2]; lp3 = lps[3];
    }
#pragma unroll
    for (int off = 16; off > 0; off >>= 1) {
        lp0 += __shfl_xor(lp0, off, 64);
        lp1 += __shfl_xor(lp1, off, 64);
        lp2 += __shfl_xor(lp2, off, 64);
        lp3 += __shfl_xor(lp3, off, 64);
    }
    if ((tid & 31) == 0) {
        s_lp[b0 + 0] = lp0; s_lp[b0 + 1] = lp1;
        s_lp[b0 + 2] = lp2; s_lp[b0 + 3] = lp3;
    }
    __syncthreads();
    if (tid < 32) lpart[(size_t)blockIdx.x * 32 + tid] = s_lp[tid];
}

// ---------------------------------------------------------------------------
// Kernel 4: inv_l[b] = 1 / sum over blocks of lpart
// ---------------------------------------------------------------------------
__global__ __launch_bounds__(256) void invl_kernel(const float* __restrict__ lpart,
                                                   float* __restrict__ inv_l) {
    int b = threadIdx.x & 31;
    int g = threadIdx.x >> 5;     // 8 groups
    float s = 0.f;
    for (int blk = g; blk < NBLKA; blk += 8)
        s += lpart[(size_t)blk * 32 + b];
    __shared__ float red[8][32];
    red[g][b] = s;
    __syncthreads();
    if (threadIdx.x < 32) {
        float t = 0.f;
#pragma unroll
        for (int gg = 0; gg < 8; ++gg) t += red[gg][threadIdx.x];
        inv_l[threadIdx.x] = 1.f / t;
    }
}

// ---------------------------------------------------------------------------
// Kernel 5 (pass B): partial[ch][b][e] = sum over chunk rows of w[b][v]*emb[v][e]
// Barrier-free: thread = e (half-row), acc[32] fully unrolled, w loads are
// wave-uniform float4 (scalar path). grid = NCH*2 blocks x 256 thr.
// ---------------------------------------------------------------------------
__global__ __launch_bounds__(256) void wsum_kernel(const float* __restrict__ emb,
                                                   const float* __restrict__ w,
                                                   float* __restrict__ partial) {
    int blk = blockIdx.x;
    int ch  = blk >> 1;
    int e   = (blk & 1) * 256 + threadIdx.x;
    int rbeg = ch * CHB;
    int rend = rbeg + CHB; if (rend > V_) rend = V_;

    float acc[32];
#pragma unroll
    for (int b = 0; b < 32; ++b) acc[b] = 0.f;

    int v4end = rbeg + ((rend - rbeg) & ~3);
    for (int v4 = rbeg; v4 < v4end; v4 += 4) {
        float ev0 = emb[(size_t)(v4 + 0) * E_ + e];
        float ev1 = emb[(size_t)(v4 + 1) * E_ + e];
        float ev2 = emb[(size_t)(v4 + 2) * E_ + e];
        float ev3 = emb[(size_t)(v4 + 3) * E_ + e];
#pragma unroll
        for (int b = 0; b < 32; ++b) {
            float4 wq = *reinterpret_cast<const float4*>(w + (size_t)b * WPITCH + v4);
            acc[b] += wq.x * ev0 + wq.y * ev1 + wq.z * ev2 + wq.w * ev3;
        }
    }
    for (int v = v4end; v < rend; ++v) {
        float ev = emb[(size_t)v * E_ + e];
#pragma unroll
        for (int b = 0; b < 32; ++b)
            acc[b] += w[(size_t)b * WPITCH + v] * ev;
    }
#pragma unroll
    for (int b = 0; b < 32; ++b)
        partial[((size_t)ch * 32 + b) * E_ + e] = acc[b];
}

// ---------------------------------------------------------------------------
// Kernel 6/7: two-stage deterministic combine (+ normalize by inv_l)
// ---------------------------------------------------------------------------
__global__ __launch_bounds__(64) void comb1_kernel(const float* __restrict__ partial,
                                                   float* __restrict__ tmp) {
    int g   = blockIdx.x >> 8;          // 0..NG-1
    int rem = blockIdx.x & 255;
    int b   = rem >> 3;
    int e   = (rem & 7) * 64 + threadIdx.x;
    float s = 0.f;
#pragma unroll
    for (int i = 0; i < 16; ++i) {
        int c = g * 16 + i;
        if (c < NCH) s += partial[((size_t)c * 32 + b) * E_ + e];
    }
    tmp[((size_t)g * 32 + b) * E_ + e] = s;
}

__global__ __launch_bounds__(64) void comb2_kernel(const float* __restrict__ tmp,
                                                   const float* __restrict__ inv_l,
                                                   float* __restrict__ out) {
    int b = blockIdx.x >> 3;
    int e = (blockIdx.x & 7) * 64 + threadIdx.x;
    float s = 0.f;
#pragma unroll
    for (int g = 0; g < NG; ++g)
        s += tmp[((size_t)g * 32 + b) * E_ + e];
    out[(size_t)b * E_ + e] = s * inv_l[b];
}

extern "C" void kernel_launch(void* const* d_in, const int* in_sizes, int n_in,
                              void* d_out, int out_size, void* d_ws, size_t ws_size,
                              hipStream_t stream) {
    const float* h    = (const float*)d_in[0];   // [B,H]
    const int*   mems = (const int*)d_in[1];     // [B,S]
    const float* emb  = (const float*)d_in[2];   // [V,E]
    const float* W    = (const float*)d_in[3];   // [E,H]
    const float* bias = (const float*)d_in[4];   // [E]
    float* out = (float*)d_out;                  // [B,1,E]

    float* ws = (float*)d_ws;
    const size_t CNT = (size_t)B_ * V_;                       // 1,608,224
    float* vt      = ws;                                      // 16384
    int*   counts  = (int*)(ws + 16384);                      // CNT
    float* lpart   = ws + 16384 + CNT;                        // NBLKA*32
    float* inv_l   = lpart + (size_t)NBLKA * 32;              // 32
    float* w       = inv_l + 32;                              // 32*WPITCH
    float* partial = w + (size_t)32 * WPITCH;                 // NCH*32*512
    float* tmp     = partial + (size_t)NCH * 32 * E_;         // NG*32*512

    hipMemsetAsync(counts, 0, CNT * sizeof(int), stream);

    hipLaunchKernelGGL(vt_kernel, dim3(B_ * E_ / 4), dim3(256), 0, stream,
                       h, W, bias, vt);
    hipLaunchKernelGGL(hist_kernel, dim3(B_ * S_ / 256), dim3(256), 0, stream,
                       mems, counts);
    hipLaunchKernelGGL(scorew_kernel, dim3(NBLKA), dim3(256), 0, stream,
                       emb, vt, counts, w, lpart);
    hipLaunchKernelGGL(invl_kernel, dim3(1), dim3(256), 0, stream,
                       lpart, inv_l);
    hipLaunchKernelGGL(wsum_kernel, dim3(NCH * 2), dim3(256), 0, stream,
                       emb, w, partial);
    hipLaunchKernelGGL(comb1_kernel, dim3(NG * 256), dim3(64), 0, stream,
                       partial, tmp);
    hipLaunchKernelGGL(comb2_kernel, dim3(256), dim3(64), 0, stream,
                       tmp, inv_l, out);
}

// Round 8
// 163.182 us; speedup vs baseline: 1.3827x; 1.2757x over previous
//
#include <hip/hip_runtime.h>
#include <cmath>

#define B_ 32
#define S_ 4096
#define E_ 512
#define H_ 1024
#define V_ 50257
#define WPITCH 50304          // padded w row pitch
#define CHA 64                // vocab rows per scorew block
#define NBLKA 786             // ceil(V_/CHA)
#define CHB 128               // vocab rows per wsum chunk
#define NCH 393               // ceil(V_/CHB)
#define NG 25                 // ceil(NCH/16)

// ---------------------------------------------------------------------------
// Kernel 1: v_t[b,e] = tanhf(dot(h[b,:], W[e,:]) + bias[e])  (proven)
// ---------------------------------------------------------------------------
__global__ __launch_bounds__(256) void vt_kernel(const float* __restrict__ h,
                                                 const float* __restrict__ W,
                                                 const float* __restrict__ bias,
                                                 float* __restrict__ vt) {
    int wid  = threadIdx.x >> 6;
    int lane = threadIdx.x & 63;
    int out  = blockIdx.x * 4 + wid;
    int b    = out >> 9;
    int e    = out & (E_ - 1);
    const float* hrow = h + b * H_;
    const float* wrow = W + (size_t)e * H_;
    int base = lane * 16;
    float acc = 0.f;
#pragma unroll
    for (int j = 0; j < 4; ++j) {
        float4 hv = *reinterpret_cast<const float4*>(hrow + base + j * 4);
        float4 wv = *reinterpret_cast<const float4*>(wrow + base + j * 4);
        acc += hv.x * wv.x + hv.y * wv.y + hv.z * wv.z + hv.w * wv.w;
    }
#pragma unroll
    for (int off = 32; off > 0; off >>= 1) acc += __shfl_xor(acc, off, 64);
    if (lane == 0) vt[out] = tanhf(acc + bias[e]);
}

// ---------------------------------------------------------------------------
// Kernel 2: histogram counts[b][v] += 1
// ---------------------------------------------------------------------------
__global__ __launch_bounds__(256) void hist_kernel(const int* __restrict__ mems,
                                                   int* __restrict__ counts) {
    int i = blockIdx.x * 256 + threadIdx.x;
    int b = i >> 12;
    atomicAdd(counts + (size_t)b * V_ + mems[i], 1);
}

// ---------------------------------------------------------------------------
// Kernel 3 (pass A): w[b][v] = counts * exp(dot(emb[v], vt[b])) + l-partials.
// 64v x 32b tile, thread = (q, q+32) x 4b. Pad-17 float4 LDS: row q reads
// cycle all 8 bank slots (conflict-free floor). Reg-prefetch k-staging.
// ---------------------------------------------------------------------------
#define DOT4(t, e) ((t).x*(e).x + (t).y*(e).y + (t).z*(e).z + (t).w*(e).w)

__global__ __launch_bounds__(256) void scorew_kernel(const float* __restrict__ emb,
                                                     const float* __restrict__ vt,
                                                     const int* __restrict__ counts,
                                                     float* __restrict__ w,
                                                     float* __restrict__ lpart) {
    const int tid   = threadIdx.x;
    const int vbase = blockIdx.x * CHA;
    const int q  = tid & 31;
    const int bh = tid >> 5;
    const int b0 = bh * 4;

    __shared__ float4 s_emb[CHA][17];   // padded: row stride 17 f4
    __shared__ float4 s_vt[32][17];
    __shared__ float  s_lp[32];

    float acc00 = 0.f, acc01 = 0.f, acc10 = 0.f, acc11 = 0.f;
    float acc20 = 0.f, acc21 = 0.f, acc30 = 0.f, acc31 = 0.f;

    const int er0 = tid >> 4, ec = tid & 15;
    const int er1 = er0 + 16, er2 = er0 + 32, er3 = er0 + 48;
    const int vr0 = er0, vr1 = er0 + 16;

    int g0 = vbase + er0; if (g0 >= V_) g0 = V_ - 1;
    int g1 = vbase + er1; if (g1 >= V_) g1 = V_ - 1;
    int g2 = vbase + er2; if (g2 >= V_) g2 = V_ - 1;
    int g3 = vbase + er3; if (g3 >= V_) g3 = V_ - 1;

    float4 se0, se1, se2, se3, sv0, sv1;

    // prologue: stage k-tile 0
    se0 = *reinterpret_cast<const float4*>(emb + (size_t)g0 * E_ + ec * 4);
    se1 = *reinterpret_cast<const float4*>(emb + (size_t)g1 * E_ + ec * 4);
    se2 = *reinterpret_cast<const float4*>(emb + (size_t)g2 * E_ + ec * 4);
    se3 = *reinterpret_cast<const float4*>(emb + (size_t)g3 * E_ + ec * 4);
    sv0 = *reinterpret_cast<const float4*>(vt + vr0 * E_ + ec * 4);
    sv1 = *reinterpret_cast<const float4*>(vt + vr1 * E_ + ec * 4);
    s_emb[er0][ec] = se0; s_emb[er1][ec] = se1;
    s_emb[er2][ec] = se2; s_emb[er3][ec] = se3;
    s_vt[vr0][ec] = sv0;  s_vt[vr1][ec] = sv1;
    __syncthreads();

    for (int kt = 0; kt < E_; kt += 64) {
        bool more = (kt + 64) < E_;
        if (more) {
            int ko = kt + 64;
            se0 = *reinterpret_cast<const float4*>(emb + (size_t)g0 * E_ + ko + ec * 4);
            se1 = *reinterpret_cast<const float4*>(emb + (size_t)g1 * E_ + ko + ec * 4);
            se2 = *reinterpret_cast<const float4*>(emb + (size_t)g2 * E_ + ko + ec * 4);
            se3 = *reinterpret_cast<const float4*>(emb + (size_t)g3 * E_ + ko + ec * 4);
            sv0 = *reinterpret_cast<const float4*>(vt + vr0 * E_ + ko + ec * 4);
            sv1 = *reinterpret_cast<const float4*>(vt + vr1 * E_ + ko + ec * 4);
        }
#pragma unroll
        for (int k4 = 0; k4 < 16; ++k4) {
            float4 e0 = s_emb[q][k4];
            float4 e1 = s_emb[q + 32][k4];
            float4 t0 = s_vt[b0 + 0][k4];
            float4 t1 = s_vt[b0 + 1][k4];
            float4 t2 = s_vt[b0 + 2][k4];
            float4 t3 = s_vt[b0 + 3][k4];
            acc00 += DOT4(t0, e0); acc01 += DOT4(t0, e1);
            acc10 += DOT4(t1, e0); acc11 += DOT4(t1, e1);
            acc20 += DOT4(t2, e0); acc21 += DOT4(t2, e1);
            acc30 += DOT4(t3, e0); acc31 += DOT4(t3, e1);
        }
        if (more) {
            __syncthreads();
            s_emb[er0][ec] = se0; s_emb[er1][ec] = se1;
            s_emb[er2][ec] = se2; s_emb[er3][ec] = se3;
            s_vt[vr0][ec] = sv0;  s_vt[vr1][ec] = sv1;
            __syncthreads();
        }
    }

    // epilogue: w = c*exp(score); coalesced writes (lane-consecutive v)
    int v_0 = vbase + q, v_1 = vbase + q + 32;
    float a0[4] = {acc00, acc10, acc20, acc30};
    float a1[4] = {acc01, acc11, acc21, acc31};
    float lp[4];
#pragma unroll
    for (int j = 0; j < 4; ++j) {
        int b = b0 + j;
        float w0 = 0.f, w1 = 0.f;
        if (v_0 < V_) {
            int c = counts[(size_t)b * V_ + v_0];
            if (c) w0 = (float)c * __expf(a0[j]);
            w[(size_t)b * WPITCH + v_0] = w0;
        }
        if (v_1 < V_) {
            int c = counts[(size_t)b * V_ + v_1];
            if (c) w1 = (float)c * __expf(a1[j]);
            w[(size_t)b * WPITCH + v_1] = w1;
        }
        lp[j] = w0 + w1;
    }
#pragma unroll
    for (int off = 16; off > 0; off >>= 1) {
#pragma unroll
        for (int j = 0; j < 4; ++j) lp[j] += __shfl_xor(lp[j], off, 64);
    }
    if ((tid & 31) == 0) {
#pragma unroll
        for (int j = 0; j < 4; ++j) s_lp[b0 + j] = lp[j];
    }
    __syncthreads();
    if (tid < 32) lpart[(size_t)blockIdx.x * 32 + tid] = s_lp[tid];
}

// ---------------------------------------------------------------------------
// Kernel 4: inv_l[b] = 1 / sum over blocks of lpart
// ---------------------------------------------------------------------------
__global__ __launch_bounds__(256) void invl_kernel(const float* __restrict__ lpart,
                                                   float* __restrict__ inv_l) {
    int b = threadIdx.x & 31;
    int g = threadIdx.x >> 5;
    float s = 0.f;
    for (int blk = g; blk < NBLKA; blk += 8)
        s += lpart[(size_t)blk * 32 + b];
    __shared__ float red[8][32];
    red[g][b] = s;
    __syncthreads();
    if (threadIdx.x < 32) {
        float t = 0.f;
#pragma unroll
        for (int gg = 0; gg < 8; ++gg) t += red[gg][threadIdx.x];
        inv_l[threadIdx.x] = 1.f / t;
    }
}

// ---------------------------------------------------------------------------
// Kernel 5 (pass B): w-chunk staged in LDS once; inner loop = 8 ev global
// loads in flight + broadcast ds_read_b128 of w + 256 FMA. VALU-bound.
// ---------------------------------------------------------------------------
__global__ __launch_bounds__(256) void wsum_kernel(const float* __restrict__ emb,
                                                   const float* __restrict__ w,
                                                   float* __restrict__ partial) {
    int blk  = blockIdx.x;
    int ch   = blk >> 1;
    int e    = (blk & 1) * 256 + threadIdx.x;
    int rbeg = ch * CHB;

    __shared__ float s_w[32][CHB];

    // cooperative stage: thread -> (b = tid>>3, 16 floats at (tid&7)*16)
    {
        int r  = threadIdx.x >> 3;
        int c0 = (threadIdx.x & 7) * 16;
        const float* wrow = w + (size_t)r * WPITCH;
#pragma unroll
        for (int j = 0; j < 4; ++j) {
            int c = c0 + j * 4;
            int v = rbeg + c;
            float4 val = {0.f, 0.f, 0.f, 0.f};
            if (v + 3 < V_) {
                val = *reinterpret_cast<const float4*>(wrow + v);
            } else {
                if (v + 0 < V_) val.x = wrow[v + 0];
                if (v + 1 < V_) val.y = wrow[v + 1];
                if (v + 2 < V_) val.z = wrow[v + 2];
                if (v + 3 < V_) val.w = wrow[v + 3];
            }
            *reinterpret_cast<float4*>(&s_w[r][c]) = val;
        }
    }
    __syncthreads();

    float acc[32];
#pragma unroll
    for (int b = 0; b < 32; ++b) acc[b] = 0.f;

    for (int vv = 0; vv < CHB; vv += 8) {
        int vg = rbeg + vv;
        float ev0 = emb[(size_t)((vg + 0 < V_) ? vg + 0 : V_ - 1) * E_ + e];
        float ev1 = emb[(size_t)((vg + 1 < V_) ? vg + 1 : V_ - 1) * E_ + e];
        float ev2 = emb[(size_t)((vg + 2 < V_) ? vg + 2 : V_ - 1) * E_ + e];
        float ev3 = emb[(size_t)((vg + 3 < V_) ? vg + 3 : V_ - 1) * E_ + e];
        float ev4 = emb[(size_t)((vg + 4 < V_) ? vg + 4 : V_ - 1) * E_ + e];
        float ev5 = emb[(size_t)((vg + 5 < V_) ? vg + 5 : V_ - 1) * E_ + e];
        float ev6 = emb[(size_t)((vg + 6 < V_) ? vg + 6 : V_ - 1) * E_ + e];
        float ev7 = emb[(size_t)((vg + 7 < V_) ? vg + 7 : V_ - 1) * E_ + e];
#pragma unroll
        for (int b = 0; b < 32; ++b) {
            float4 wA = *reinterpret_cast<const float4*>(&s_w[b][vv]);
            float4 wB = *reinterpret_cast<const float4*>(&s_w[b][vv + 4]);
            acc[b] += wA.x * ev0 + wA.y * ev1 + wA.z * ev2 + wA.w * ev3
                    + wB.x * ev4 + wB.y * ev5 + wB.z * ev6 + wB.w * ev7;
        }
    }
#pragma unroll
    for (int b = 0; b < 32; ++b)
        partial[((size_t)ch * 32 + b) * E_ + e] = acc[b];
}

// ---------------------------------------------------------------------------
// Kernel 6/7: two-stage deterministic combine (+ normalize by inv_l)
// ---------------------------------------------------------------------------
__global__ __launch_bounds__(64) void comb1_kernel(const float* __restrict__ partial,
                                                   float* __restrict__ tmp) {
    int g   = blockIdx.x >> 8;
    int rem = blockIdx.x & 255;
    int b   = rem >> 3;
    int e   = (rem & 7) * 64 + threadIdx.x;
    float s = 0.f;
#pragma unroll
    for (int i = 0; i < 16; ++i) {
        int c = g * 16 + i;
        if (c < NCH) s += partial[((size_t)c * 32 + b) * E_ + e];
    }
    tmp[((size_t)g * 32 + b) * E_ + e] = s;
}

__global__ __launch_bounds__(64) void comb2_kernel(const float* __restrict__ tmp,
                                                   const float* __restrict__ inv_l,
                                                   float* __restrict__ out) {
    int b = blockIdx.x >> 3;
    int e = (blockIdx.x & 7) * 64 + threadIdx.x;
    float s = 0.f;
#pragma unroll
    for (int g = 0; g < NG; ++g)
        s += tmp[((size_t)g * 32 + b) * E_ + e];
    out[(size_t)b * E_ + e] = s * inv_l[b];
}

extern "C" void kernel_launch(void* const* d_in, const int* in_sizes, int n_in,
                              void* d_out, int out_size, void* d_ws, size_t ws_size,
                              hipStream_t stream) {
    const float* h    = (const float*)d_in[0];   // [B,H]
    const int*   mems = (const int*)d_in[1];     // [B,S]
    const float* emb  = (const float*)d_in[2];   // [V,E]
    const float* W    = (const float*)d_in[3];   // [E,H]
    const float* bias = (const float*)d_in[4];   // [E]
    float* out = (float*)d_out;                  // [B,1,E]

    float* ws = (float*)d_ws;
    const size_t CNT = (size_t)B_ * V_;
    float* vt      = ws;                                      // 16384
    int*   counts  = (int*)(ws + 16384);                      // CNT
    float* lpart   = ws + 16384 + CNT;                        // NBLKA*32
    float* inv_l   = lpart + (size_t)NBLKA * 32;              // 32
    float* w       = inv_l + 32;                              // 32*WPITCH
    float* partial = w + (size_t)32 * WPITCH;                 // NCH*32*512
    float* tmp     = partial + (size_t)NCH * 32 * E_;         // NG*32*512

    hipMemsetAsync(counts, 0, CNT * sizeof(int), stream);

    hipLaunchKernelGGL(vt_kernel, dim3(B_ * E_ / 4), dim3(256), 0, stream,
                       h, W, bias, vt);
    hipLaunchKernelGGL(hist_kernel, dim3(B_ * S_ / 256), dim3(256), 0, stream,
                       mems, counts);
    hipLaunchKernelGGL(scorew_kernel, dim3(NBLKA), dim3(256), 0, stream,
                       emb, vt, counts, w, lpart);
    hipLaunchKernelGGL(invl_kernel, dim3(1), dim3(256), 0, stream,
                       lpart, inv_l);
    hipLaunchKernelGGL(wsum_kernel, dim3(NCH * 2), dim3(256), 0, stream,
                       emb, w, partial);
    hipLaunchKernelGGL(comb1_kernel, dim3(NG * 256), dim3(64), 0, stream,
                       partial, tmp);
    hipLaunchKernelGGL(comb2_kernel, dim3(256), dim3(64), 0, stream,
                       tmp, inv_l, out);
}